// Round 10
// baseline (1393.945 us; speedup 1.0000x reference)
//
#include <hip/hip_runtime.h>
#include <hip/hip_bf16.h>

#define DIMX 1024
#define DSTATE 16
#define DCONV 4
#define DINNER 2048
#define DTRANK 64
#define BB 4
#define LSEQ 2048
#define BL (BB * LSEQ) /* 8192 */
#define CCHUNK 32
#define CLEN (LSEQ / CCHUNK) /* 64 */

typedef unsigned short u16;
typedef unsigned int u32;
typedef __attribute__((ext_vector_type(8))) short bf16x8;
typedef __attribute__((ext_vector_type(4))) float f32x4;

__device__ __forceinline__ float bf2f(u16 u) {
    union { u32 i; float f; } v; v.i = ((u32)u) << 16; return v.f;
}
__device__ __forceinline__ u16 f2bf(float f) {
    union { float f; u32 i; } v; v.f = f;
    u32 r = v.i + 0x7fff + ((v.i >> 16) & 1);
    return (u16)(r >> 16);
}
__device__ __forceinline__ void unpack8(bf16x8 v, float* f) {
    union { bf16x8 v; u32 u[4]; } q; q.v = v;
#pragma unroll
    for (int i = 0; i < 4; ++i) {
        union { u32 i; float f; } lo, hi;
        lo.i = q.u[i] << 16;
        hi.i = q.u[i] & 0xffff0000u;
        f[2 * i] = lo.f; f[2 * i + 1] = hi.f;
    }
}
__device__ __forceinline__ uint4 pack8(const float* f) {
    uint4 r;
    r.x = (u32)f2bf(f[0]) | ((u32)f2bf(f[1]) << 16);
    r.y = (u32)f2bf(f[2]) | ((u32)f2bf(f[3]) << 16);
    r.z = (u32)f2bf(f[4]) | ((u32)f2bf(f[5]) << 16);
    r.w = (u32)f2bf(f[6]) | ((u32)f2bf(f[7]) << 16);
    return r;
}
// async global->LDS, 16B per lane; lds base must be wave-uniform (HW adds lane*16)
__device__ __forceinline__ void load_lds_16(const u16* g, u16* l) {
    __builtin_amdgcn_global_load_lds((const __attribute__((address_space(1))) u32*)g,
                                     (__attribute__((address_space(3))) u32*)l, 16, 0, 0);
}

// ---- batched f32 -> bf16 convert for W_in / W_x / W_dt in one launch ----
#define N_WIN (2 * DINNER * DIMX)            /* 8388608 */
#define N_WX ((DTRANK + 2 * DSTATE) * DINNER) /* 196608 */
#define N_WDT (DINNER * DTRANK)              /* 131072 */
__global__ __launch_bounds__(256) void cvt_weights(const float* __restrict__ w_in,
                                                   const float* __restrict__ w_x,
                                                   const float* __restrict__ w_dt,
                                                   u16* __restrict__ o_in,
                                                   u16* __restrict__ o_x,
                                                   u16* __restrict__ o_dt) {
    int i = (blockIdx.x * 256 + threadIdx.x) * 4;
    const float* s; u16* d;
    if (i < N_WIN) { s = w_in + i; d = o_in + i; }
    else if (i < N_WIN + N_WX) { s = w_x + (i - N_WIN); d = o_x + (i - N_WIN); }
    else if (i < N_WIN + N_WX + N_WDT) { s = w_dt + (i - N_WIN - N_WX); d = o_dt + (i - N_WIN - N_WX); }
    else return;
    float4 f = *(const float4*)s;
    u32 p0 = (u32)f2bf(f.x) | ((u32)f2bf(f.y) << 16);
    u32 p1 = (u32)f2bf(f.z) | ((u32)f2bf(f.w) << 16);
    *(uint2*)d = make_uint2(p0, p1);
}

__global__ __launch_bounds__(256) void cvt_bf16(const float* __restrict__ src,
                                                u16* __restrict__ dst, int n) {
    int i = (blockIdx.x * 256 + threadIdx.x) * 4;
    if (i < n) {
        float4 f = *(const float4*)(src + i);
        u32 p0 = (u32)f2bf(f.x) | ((u32)f2bf(f.y) << 16);
        u32 p1 = (u32)f2bf(f.z) | ((u32)f2bf(f.w) << 16);
        *(uint2*)(dst + i) = make_uint2(p0, p1);
    }
}

// ---------------- LayerNorm: 1 block per row of 1024, f32 in -> bf16 out ----------------
__global__ __launch_bounds__(256) void ln_kernel(const float* __restrict__ x,
                                                 const float* __restrict__ g,
                                                 const float* __restrict__ bta,
                                                 u16* __restrict__ xn) {
    int row = blockIdx.x;
    int tid = threadIdx.x;
    const float* xr = x + (size_t)row * DIMX;
    float4 v = *(const float4*)(xr + tid * 4);
    float s = v.x + v.y + v.z + v.w;
    float s2 = v.x * v.x + v.y * v.y + v.z * v.z + v.w * v.w;
#pragma unroll
    for (int off = 32; off >= 1; off >>= 1) {
        s  += __shfl_down(s, off);
        s2 += __shfl_down(s2, off);
    }
    __shared__ float ss[4], ss2[4];
    if ((tid & 63) == 0) { ss[tid >> 6] = s; ss2[tid >> 6] = s2; }
    __syncthreads();
    s  = ss[0] + ss[1] + ss[2] + ss[3];
    s2 = ss2[0] + ss2[1] + ss2[2] + ss2[3];
    float mu = s * (1.f / DIMX);
    float var = s2 * (1.f / DIMX) - mu * mu;
    float rs = rsqrtf(var + 1e-5f);
    float4 gv = *(const float4*)(g + tid * 4);
    float4 bv = *(const float4*)(bta + tid * 4);
    float o0 = (v.x - mu) * rs * gv.x + bv.x;
    float o1 = (v.y - mu) * rs * gv.y + bv.y;
    float o2 = (v.z - mu) * rs * gv.z + bv.z;
    float o3 = (v.w - mu) * rs * gv.w + bv.w;
    u32 p0 = (u32)f2bf(o0) | ((u32)f2bf(o1) << 16);
    u32 p1 = (u32)f2bf(o2) | ((u32)f2bf(o3) << 16);
    *(uint2*)(xn + (size_t)row * DIMX + tid * 4) = make_uint2(p0, p1);
}

// ------- bf16 MFMA GEMM, global_load_lds staging + XOR-swizzled LDS: C = A*B^T -------
template <int EPI>
__global__ __launch_bounds__(256) void gemm_bt(const u16* __restrict__ A,
                                               const u16* __restrict__ Bm,
                                               u16* __restrict__ C,
                                               float* __restrict__ Cf,
                                               u16* __restrict__ C2,
                                               const float* __restrict__ Xf,
                                               int M, int N, int K,
                                               int lda, int ldb, int ldc) {
    __shared__ __align__(16) u16 As[128 * 32];
    __shared__ __align__(16) u16 Bs[128 * 32];
    int tid = threadIdx.x;
    int bm = blockIdx.x, bn = blockIdx.y;
    int wave = tid >> 6, lane = tid & 63;
    int wm = (wave >> 1) * 64, wn = (wave & 1) * 64;
    int lr = lane & 15;
    int lq = lane >> 4;
    int srow = lane >> 2;
    int scol = (((lane & 3) ^ ((lane >> 3) & 3)) * 8);
    int rblk = (lq ^ ((lr >> 1) & 3)) * 8;

    f32x4 acc[4][4];
#pragma unroll
    for (int i = 0; i < 4; ++i)
#pragma unroll
        for (int j = 0; j < 4; ++j) acc[i][j] = (f32x4){0.f, 0.f, 0.f, 0.f};

    for (int k0 = 0; k0 < K; k0 += 32) {
#pragma unroll
        for (int rep = 0; rep < 2; ++rep) {
            int chunk = wave * 2 + rep;
            int arow = bm * 128 + chunk * 16 + srow;
            load_lds_16(A + (size_t)arow * lda + k0 + scol, &As[chunk * 512]);
            int brow = bn * 128 + chunk * 16 + srow;
            if (brow < N)
                load_lds_16(Bm + (size_t)brow * ldb + k0 + scol, &Bs[chunk * 512]);
        }
        __syncthreads();
        bf16x8 af[4], bfr[4];
#pragma unroll
        for (int i = 0; i < 4; ++i)
            af[i] = *(bf16x8*)(&As[(wm + i * 16 + lr) * 32 + rblk]);
#pragma unroll
        for (int j = 0; j < 4; ++j)
            bfr[j] = *(bf16x8*)(&Bs[(wn + j * 16 + lr) * 32 + rblk]);
#pragma unroll
        for (int i = 0; i < 4; ++i)
#pragma unroll
            for (int j = 0; j < 4; ++j)
                acc[i][j] = __builtin_amdgcn_mfma_f32_16x16x32_bf16(af[i], bfr[j], acc[i][j], 0, 0, 0);
        __syncthreads();
    }

#pragma unroll
    for (int i = 0; i < 4; ++i)
#pragma unroll
        for (int j = 0; j < 4; ++j) {
            int col = bn * 128 + wn + j * 16 + lr;
            if (col >= N) continue;
#pragma unroll
            for (int r = 0; r < 4; ++r) {
                int row = bm * 128 + wm + i * 16 + lq * 4 + r;
                float v = acc[i][j][r];
                size_t off = (size_t)row * ldc + col;
                if (EPI == 2) {
                    v += Xf[off];
                    Cf[off] = v;
                } else if (EPI == 3) {
                    if (col < DINNER) {
                        C[(size_t)row * DINNER + col] = f2bf(v);
                    } else {
                        float s = v / (1.f + __expf(-v));
                        C2[(size_t)row * DINNER + (col - DINNER)] = f2bf(s);
                    }
                } else {
                    C[off] = f2bf(v);
                }
            }
        }
}

// ------- Split-K variant for GEMM4 (N=96): f32 partials, ldc=96, grid.z = split -------
__global__ __launch_bounds__(256) void gemm_bt_splitk(const u16* __restrict__ A,
                                                      const u16* __restrict__ Bm,
                                                      float* __restrict__ Cp,
                                                      int M, int N, int K,
                                                      int lda, int ldb, int nsplit) {
    __shared__ __align__(16) u16 As[128 * 32];
    __shared__ __align__(16) u16 Bs[128 * 32];
    int tid = threadIdx.x;
    int bm = blockIdx.x, split = blockIdx.z;
    int ks = K / nsplit;
    int kbeg = split * ks, kend = kbeg + ks;
    int wave = tid >> 6, lane = tid & 63;
    int wm = (wave >> 1) * 64, wn = (wave & 1) * 64;
    int lr = lane & 15;
    int lq = lane >> 4;
    int srow = lane >> 2;
    int scol = (((lane & 3) ^ ((lane >> 3) & 3)) * 8);
    int rblk = (lq ^ ((lr >> 1) & 3)) * 8;

    f32x4 acc[4][4];
#pragma unroll
    for (int i = 0; i < 4; ++i)
#pragma unroll
        for (int j = 0; j < 4; ++j) acc[i][j] = (f32x4){0.f, 0.f, 0.f, 0.f};

    for (int k0 = kbeg; k0 < kend; k0 += 32) {
#pragma unroll
        for (int rep = 0; rep < 2; ++rep) {
            int chunk = wave * 2 + rep;
            int arow = bm * 128 + chunk * 16 + srow;
            load_lds_16(A + (size_t)arow * lda + k0 + scol, &As[chunk * 512]);
            int brow = chunk * 16 + srow;
            if (brow < N)
                load_lds_16(Bm + (size_t)brow * ldb + k0 + scol, &Bs[chunk * 512]);
        }
        __syncthreads();
        bf16x8 af[4], bfr[4];
#pragma unroll
        for (int i = 0; i < 4; ++i)
            af[i] = *(bf16x8*)(&As[(wm + i * 16 + lr) * 32 + rblk]);
#pragma unroll
        for (int j = 0; j < 4; ++j)
            bfr[j] = *(bf16x8*)(&Bs[(wn + j * 16 + lr) * 32 + rblk]);
#pragma unroll
        for (int i = 0; i < 4; ++i)
#pragma unroll
            for (int j = 0; j < 4; ++j)
                acc[i][j] = __builtin_amdgcn_mfma_f32_16x16x32_bf16(af[i], bfr[j], acc[i][j], 0, 0, 0);
        __syncthreads();
    }

#pragma unroll
    for (int i = 0; i < 4; ++i)
#pragma unroll
        for (int j = 0; j < 4; ++j) {
            int col = wn + j * 16 + lr;
            if (col >= N) continue;
#pragma unroll
            for (int r = 0; r < 4; ++r) {
                int row = bm * 128 + wm + i * 16 + lq * 4 + r;
                Cp[((size_t)split * M + row) * 96 + col] = acc[i][j][r];
            }
        }
}

// reduce 4 split-K partials -> bf16 xdbl
__global__ __launch_bounds__(256) void reduce4(const float* __restrict__ Cp,
                                               u16* __restrict__ xdbl) {
    int t = blockIdx.x * 256 + threadIdx.x;  // 8192*96
    const size_t S = (size_t)BL * 96;
    float s = Cp[t] + Cp[t + S] + Cp[t + 2 * S] + Cp[t + 3 * S];
    xdbl[t] = f2bf(s);
}

// ------- dedicated skinny-K GEMM: dt = softplus(xdbl[:, :64] * W_dt^T + b_dt) -------
__global__ __launch_bounds__(256) void dt_kernel(const u16* __restrict__ A,   // xdbl, lda=96
                                                 const u16* __restrict__ Bw,  // W_dt bf16 [2048][64]
                                                 const float* __restrict__ bias,
                                                 u16* __restrict__ C) {       // dt [8192][2048]
    __shared__ __align__(16) u16 Bs[128 * 64];  // 16 KB
    int tid = threadIdx.x;
    int bm = blockIdx.x, bn = blockIdx.y;
    int wave = tid >> 6, lane = tid & 63;
    int wm = (wave >> 1) * 64, wn = (wave & 1) * 64;
    int lr = lane & 15;
    int lq = lane >> 4;

    const u16* bsrc = Bw + (size_t)bn * 128 * 64;
    {
        int row = tid >> 1, bb = (tid & 1) * 4;
#pragma unroll
        for (int j = 0; j < 4; ++j) {
            int b = bb + j;
            *(uint4*)(&Bs[row * 64 + ((b ^ (row & 7)) * 8)]) =
                *(const uint4*)(bsrc + row * 64 + b * 8);
        }
    }

    bf16x8 af[4][2];
#pragma unroll
    for (int i = 0; i < 4; ++i)
#pragma unroll
        for (int kk = 0; kk < 2; ++kk)
            af[i][kk] = *(const bf16x8*)(A + (size_t)(bm * 128 + wm + i * 16 + lr) * 96 + kk * 32 + lq * 8);

    __syncthreads();

    f32x4 acc[4][4];
#pragma unroll
    for (int i = 0; i < 4; ++i)
#pragma unroll
        for (int j = 0; j < 4; ++j) acc[i][j] = (f32x4){0.f, 0.f, 0.f, 0.f};

#pragma unroll
    for (int kk = 0; kk < 2; ++kk) {
        bf16x8 bfr[4];
#pragma unroll
        for (int j = 0; j < 4; ++j)
            bfr[j] = *(bf16x8*)(&Bs[(wn + j * 16 + lr) * 64 + (((kk * 4 + lq) ^ (lr & 7)) * 8)]);
#pragma unroll
        for (int i = 0; i < 4; ++i)
#pragma unroll
            for (int j = 0; j < 4; ++j)
                acc[i][j] = __builtin_amdgcn_mfma_f32_16x16x32_bf16(af[i][kk], bfr[j], acc[i][j], 0, 0, 0);
    }

#pragma unroll
    for (int i = 0; i < 4; ++i)
#pragma unroll
        for (int j = 0; j < 4; ++j) {
            int col = bn * 128 + wn + j * 16 + lr;
            float bv = bias[col];
#pragma unroll
            for (int r = 0; r < 4; ++r) {
                int row = bm * 128 + wm + i * 16 + lq * 4 + r;
                float v = acc[i][j][r] + bv;
                v = (v > 15.f) ? v : __logf(1.f + __expf(v));
                C[(size_t)row * DINNER + col] = f2bf(v);
            }
        }
}

// ---------------- Depthwise causal conv (k=4) + bias + SiLU, 8 channels/thread ----------------
__global__ __launch_bounds__(256) void conv_silu(const u16* __restrict__ u,
                                                 const float* __restrict__ cw,
                                                 const float* __restrict__ cb,
                                                 u16* __restrict__ uc) {
    size_t t = (size_t)blockIdx.x * 256 + threadIdx.x;  // over BL * DINNER/8
    int c8 = (int)(t & (DINNER / 8 - 1)) * 8;
    size_t bl = t >> 8;
    int l = (int)(bl & (LSEQ - 1));
    int b = (int)(bl >> 11);

    float wk[8][4];
#pragma unroll
    for (int i = 0; i < 8; ++i) {
        float4 w = *(const float4*)(cw + (c8 + i) * DCONV);
        wk[i][0] = w.x; wk[i][1] = w.y; wk[i][2] = w.z; wk[i][3] = w.w;
    }
    float acc[8];
    {
        float4 b0 = *(const float4*)(cb + c8);
        float4 b1 = *(const float4*)(cb + c8 + 4);
        acc[0] = b0.x; acc[1] = b0.y; acc[2] = b0.z; acc[3] = b0.w;
        acc[4] = b1.x; acc[5] = b1.y; acc[6] = b1.z; acc[7] = b1.w;
    }
#pragma unroll
    for (int k = 0; k < DCONV; ++k) {
        int ls = l + k - (DCONV - 1);
        if (ls >= 0) {
            float uf[8];
            unpack8(*(const bf16x8*)(u + ((size_t)b * LSEQ + ls) * DINNER + c8), uf);
#pragma unroll
            for (int i = 0; i < 8; ++i) acc[i] += uf[i] * wk[i][k];
        }
    }
    float o[8];
#pragma unroll
    for (int i = 0; i < 8; ++i) o[i] = acc[i] / (1.f + __expf(-acc[i]));
    *(uint4*)(uc + bl * DINNER + c8) = pack8(o);
}

// ---- Chunked selective scan, thread-per-d; dt/uc(/sz) staged in LDS 16-step tiles ----
__global__ __launch_bounds__(256, 4) void scan_pass1(const u16* __restrict__ dt,
                                                     const u16* __restrict__ uc,
                                                     const u16* __restrict__ xdbl,
                                                     const float* __restrict__ Alog,
                                                     u16* __restrict__ Pa,
                                                     u16* __restrict__ Sa) {
    __shared__ __align__(16) u16 bc[CLEN * 16];   // 2 KB  B tile [l][n]
    __shared__ __align__(16) u16 sdt[16 * 256];   // 8 KB
    __shared__ __align__(16) u16 suc[16 * 256];   // 8 KB
    int tid = threadIdx.x;
    int dbase = blockIdx.x * 256;
    int d = dbase + tid;
    int c = blockIdx.y, b = blockIdx.z;
    size_t base = (size_t)b * LSEQ + (size_t)c * CLEN;
    if (tid < CLEN * 2)
        ((uint4*)bc)[tid] = *(const uint4*)(xdbl + (base + (tid >> 1)) * 96 + 64 + (tid & 1) * 8);

    float a[16];
    const float* Ap = Alog + (size_t)d * DSTATE;
#pragma unroll
    for (int n = 0; n < 16; ++n) a[n] = -__expf(Ap[n]);
    float h[16];
#pragma unroll
    for (int n = 0; n < 16; ++n) h[n] = 0.f;
    float sum_dt = 0.f;

    const u16* dtp = dt + base * DINNER + dbase;
    const u16* ucp = uc + base * DINNER + dbase;
    for (int l0 = 0; l0 < CLEN; l0 += 16) {
        __syncthreads();
#pragma unroll
        for (int k = 0; k < 2; ++k) {
            int f = tid + k * 256, r = f >> 5, c8 = (f & 31) * 8;
            *(uint4*)(&sdt[r * 256 + c8]) = *(const uint4*)(dtp + (size_t)(l0 + r) * DINNER + c8);
            *(uint4*)(&suc[r * 256 + c8]) = *(const uint4*)(ucp + (size_t)(l0 + r) * DINNER + c8);
        }
        __syncthreads();
#pragma unroll
        for (int r = 0; r < 16; ++r) {
            float dtv = bf2f(sdt[r * 256 + tid]);
            float du  = dtv * bf2f(suc[r * 256 + tid]);
            sum_dt += dtv;
            float Bv[16];
            unpack8(*(bf16x8*)(&bc[(l0 + r) * 16]), Bv);
            unpack8(*(bf16x8*)(&bc[(l0 + r) * 16 + 8]), Bv + 8);
#pragma unroll
            for (int n = 0; n < 16; ++n) {
                float dA = __expf(dtv * a[n]);
                h[n] = dA * h[n] + du * Bv[n];
            }
        }
    }
    float P[16];
#pragma unroll
    for (int n = 0; n < 16; ++n) P[n] = __expf(a[n] * sum_dt);  // = prod(dA), exact algebra
    size_t idx = (((size_t)b * CCHUNK + c) * DINNER + d) * DSTATE;
    *(uint4*)(Pa + idx)     = pack8(P);
    *(uint4*)(Pa + idx + 8) = pack8(P + 8);
    *(uint4*)(Sa + idx)     = pack8(h);
    *(uint4*)(Sa + idx + 8) = pack8(h + 8);
}

__global__ __launch_bounds__(256) void scan_combine(u16* __restrict__ Pa,
                                                    const u16* __restrict__ Sa) {
    int t = blockIdx.x * 256 + threadIdx.x;  // over B * DINNER * 16 = 131072
    int b = t >> 15, dn = t & 32767;
    size_t base = (size_t)b * CCHUNK * (DINNER * DSTATE) + dn;
    float h = 0.f;
#pragma unroll
    for (int c = 0; c < CCHUNK; ++c) {
        size_t i = base + (size_t)c * (DINNER * DSTATE);
        float p = bf2f(Pa[i]), s = bf2f(Sa[i]);
        Pa[i] = f2bf(h);  // h_in for this chunk
        h = p * h + s;
    }
}

__global__ __launch_bounds__(256, 4) void scan_pass3(const u16* __restrict__ dt,
                                                     const u16* __restrict__ uc,
                                                     const u16* __restrict__ sz,
                                                     const u16* __restrict__ xdbl,
                                                     const float* __restrict__ Alog,
                                                     const float* __restrict__ Dv,
                                                     const u16* __restrict__ Hin,
                                                     u16* __restrict__ y) {
    __shared__ __align__(16) u16 bc[CLEN * 32];   // 4 KB  [l][0:16]=B, [16:32]=C
    __shared__ __align__(16) u16 sdt[16 * 256];   // 8 KB
    __shared__ __align__(16) u16 suc[16 * 256];   // 8 KB
    __shared__ __align__(16) u16 ssz[16 * 256];   // 8 KB
    int tid = threadIdx.x;
    int dbase = blockIdx.x * 256;
    int d = dbase + tid;
    int c = blockIdx.y, b = blockIdx.z;
    size_t base = (size_t)b * LSEQ + (size_t)c * CLEN;
    ((uint4*)bc)[tid] = *(const uint4*)(xdbl + (base + (tid >> 2)) * 96 + 64 + (tid & 3) * 8);

    float a[16];
    const float* Ap = Alog + (size_t)d * DSTATE;
#pragma unroll
    for (int n = 0; n < 16; ++n) a[n] = -__expf(Ap[n]);
    float Dd = Dv[d];
    float h[16];
    size_t idx = (((size_t)b * CCHUNK + c) * DINNER + d) * DSTATE;
    unpack8(*(bf16x8*)(Hin + idx), h);
    unpack8(*(bf16x8*)(Hin + idx + 8), h + 8);

    const u16* dtp = dt + base * DINNER + dbase;
    const u16* ucp = uc + base * DINNER + dbase;
    const u16* szp = sz + base * DINNER + dbase;
    u16* yp        = y  + base * DINNER + d;
    for (int l0 = 0; l0 < CLEN; l0 += 16) {
        __syncthreads();
#pragma unroll
        for (int k = 0; k < 2; ++k) {
            int f = tid + k * 256, r = f >> 5, c8 = (f & 31) * 8;
            size_t off = (size_t)(l0 + r) * DINNER + c8;
            *(uint4*)(&sdt[r * 256 + c8]) = *(const uint4*)(dtp + off);
            *(uint4*)(&suc[r * 256 + c8]) = *(const uint4*)(ucp + off);
            *(uint4*)(&ssz[r * 256 + c8]) = *(const uint4*)(szp + off);
        }
        __syncthreads();
#pragma unroll
        for (int r = 0; r < 16; ++r) {
            float dtv = bf2f(sdt[r * 256 + tid]);
            float ucv = bf2f(suc[r * 256 + tid]);
            float du  = dtv * ucv;
            float Bv[16], Cv[16];
            unpack8(*(bf16x8*)(&bc[(l0 + r) * 32]), Bv);
            unpack8(*(bf16x8*)(&bc[(l0 + r) * 32 + 8]), Bv + 8);
            unpack8(*(bf16x8*)(&bc[(l0 + r) * 32 + 16]), Cv);
            unpack8(*(bf16x8*)(&bc[(l0 + r) * 32 + 24]), Cv + 8);
            float yv = 0.f;
#pragma unroll
            for (int n = 0; n < 16; ++n) {
                float dA = __expf(dtv * a[n]);
                h[n] = dA * h[n] + du * Bv[n];
                yv += h[n] * Cv[n];
            }
            float szv = bf2f(ssz[r * 256 + tid]);  // already silu(z)
            yp[(size_t)(l0 + r) * DINNER] = f2bf((yv + ucv * Dd) * szv);
        }
    }
}

extern "C" void kernel_launch(void* const* d_in, const int* in_sizes, int n_in,
                              void* d_out, int out_size, void* d_ws, size_t ws_size,
                              hipStream_t stream) {
    const float* x      = (const float*)d_in[0];
    const float* ln_g   = (const float*)d_in[1];
    const float* ln_b   = (const float*)d_in[2];
    const float* W_in   = (const float*)d_in[3];
    const float* conv_w = (const float*)d_in[4];
    const float* conv_b = (const float*)d_in[5];
    const float* W_x    = (const float*)d_in[6];
    const float* W_dt   = (const float*)d_in[7];
    const float* b_dt   = (const float*)d_in[8];
    const float* A_log  = (const float*)d_in[9];
    const float* Dvec   = (const float*)d_in[10];
    const float* W_out  = (const float*)d_in[11];
    float* out = (float*)d_out;

    // ws (130 MB):
    //   [0, 1.5MB)       xdbl (bf16)
    //   [1.5MB, 1.75MB)  W_dt bf16
    //   [2,34)           u (dead after conv; y reuses)
    //   [34,66)          sz = silu(z)  (dead after pass3; W_out bf16 here)
    //   [66,98)          uc
    //   [98,130)         dt  -- pre-dt carries W_in bf16 [98,106), W_x bf16 [106,106.4)
    // d_out (32MB f32): xn bf16 [0:16MB] (LN->GEMM1); splitK partials f32 [0:12.6MB];
    // Pa bf16 [0:8.4MB](->Hin in-place), Sa bf16 [16:24.4MB]; final GEMM overwrites.
    char* ws = (char*)d_ws;
    u16* xdbl   = (u16*)(ws);
    u16* wdt_b  = (u16*)(ws + (size_t)1572864);
    u16* u      = (u16*)(ws + (size_t)(2u << 20));
    u16* y      = u;
    u16* sz     = (u16*)(ws + (size_t)(34u << 20));
    u16* wout_b = (u16*)(ws + (size_t)(34u << 20));
    u16* uc     = (u16*)(ws + (size_t)(66u << 20));
    u16* dt     = (u16*)(ws + (size_t)(98u << 20));
    u16* win_b  = (u16*)(ws + (size_t)(98u << 20));
    u16* wx_b   = (u16*)(ws + (size_t)(106u << 20));
    u16* xn     = (u16*)d_out;
    float* c4p  = (float*)d_out;
    u16* Pa     = (u16*)d_out;
    u16* Sa     = (u16*)((char*)d_out + (size_t)(16u << 20));

    // 0. weight conversions (f32 -> bf16), one batched launch
    cvt_weights<<<(N_WIN + N_WX + N_WDT) / 1024, 256, 0, stream>>>(W_in, W_x, W_dt,
                                                                   win_b, wx_b, wdt_b);

    // 1. LayerNorm (f32 -> bf16)
    ln_kernel<<<BL, 256, 0, stream>>>(x, ln_g, ln_b, xn);

    // 2. [u | silu(z)] = xn * W_in^T   (M=8192, N=4096, K=1024)
    gemm_bt<3><<<dim3(64, 32), 256, 0, stream>>>(xn, win_b, u, nullptr, sz, nullptr,
                                                 BL, 2 * DINNER, DIMX, DIMX, DIMX, 2 * DINNER);

    // 3. depthwise conv + bias + silu (8 ch/thread)
    conv_silu<<<(BL * DINNER / 8) / 256, 256, 0, stream>>>(u, conv_w, conv_b, uc);

    // 4. x_dbl = uc * W_x^T  (M=8192, N=96, K=2048), split-K x4 + reduce
    gemm_bt_splitk<<<dim3(64, 1, 4), 256, 0, stream>>>(uc, wx_b, c4p,
                                                       BL, DTRANK + 2 * DSTATE, DINNER,
                                                       DINNER, DINNER, 4);
    reduce4<<<(BL * 96) / 256, 256, 0, stream>>>(c4p, xdbl);

    // 5. dt = softplus(x_dbl[:, :64] * W_dt^T + b_dt)
    dt_kernel<<<dim3(64, 16), 256, 0, stream>>>(xdbl, wdt_b, b_dt, dt);

    // 6. chunked selective scan -> y (LDS-staged streaming operands)
    scan_pass1<<<dim3(DINNER / 256, CCHUNK, BB), 256, 0, stream>>>(dt, uc, xdbl, A_log, Pa, Sa);
    scan_combine<<<(BB * DINNER * DSTATE) / 256, 256, 0, stream>>>(Pa, Sa);
    scan_pass3<<<dim3(DINNER / 256, CCHUNK, BB), 256, 0, stream>>>(dt, uc, sz, xdbl, A_log, Dvec, Pa, y);

    // 6b. convert W_out now that sz is dead
    cvt_bf16<<<2048, 256, 0, stream>>>(W_out, wout_b, DIMX * DINNER);

    // 7. out = x + y * W_out^T  (M=8192, N=1024, K=2048), f32 output
    gemm_bt<2><<<dim3(64, 8), 256, 0, stream>>>(y, wout_b, nullptr, out, nullptr, x,
                                                BL, DIMX, DINNER, DINNER, DINNER, DIMX);
}

// Round 11
// 524.627 us; speedup vs baseline: 2.6570x; 2.6570x over previous
//
#include <hip/hip_runtime.h>
#include <hip/hip_bf16.h>

#define DIMX 1024
#define DSTATE 16
#define DCONV 4
#define DINNER 2048
#define DTRANK 64
#define BB 4
#define LSEQ 2048
#define BL (BB * LSEQ) /* 8192 */
#define CCHUNK 32
#define CLEN (LSEQ / CCHUNK) /* 64 */

typedef unsigned short u16;
typedef unsigned int u32;
typedef __attribute__((ext_vector_type(8))) short bf16x8;
typedef __attribute__((ext_vector_type(4))) float f32x4;

__device__ __forceinline__ float bf2f(u16 u) {
    union { u32 i; float f; } v; v.i = ((u32)u) << 16; return v.f;
}
__device__ __forceinline__ u16 f2bf(float f) {
    union { float f; u32 i; } v; v.f = f;
    u32 r = v.i + 0x7fff + ((v.i >> 16) & 1);
    return (u16)(r >> 16);
}
__device__ __forceinline__ void unpack8(bf16x8 v, float* f) {
    union { bf16x8 v; u32 u[4]; } q; q.v = v;
#pragma unroll
    for (int i = 0; i < 4; ++i) {
        union { u32 i; float f; } lo, hi;
        lo.i = q.u[i] << 16;
        hi.i = q.u[i] & 0xffff0000u;
        f[2 * i] = lo.f; f[2 * i + 1] = hi.f;
    }
}
__device__ __forceinline__ uint4 pack8(const float* f) {
    uint4 r;
    r.x = (u32)f2bf(f[0]) | ((u32)f2bf(f[1]) << 16);
    r.y = (u32)f2bf(f[2]) | ((u32)f2bf(f[3]) << 16);
    r.z = (u32)f2bf(f[4]) | ((u32)f2bf(f[5]) << 16);
    r.w = (u32)f2bf(f[6]) | ((u32)f2bf(f[7]) << 16);
    return r;
}
// async global->LDS, 16B per lane; lds base must be wave-uniform (HW adds lane*16)
__device__ __forceinline__ void load_lds_16(const u16* g, u16* l) {
    __builtin_amdgcn_global_load_lds((const __attribute__((address_space(1))) u32*)g,
                                     (__attribute__((address_space(3))) u32*)l, 16, 0, 0);
}

// ---- batched f32 -> bf16 convert for W_in / W_x / W_dt in one launch ----
#define N_WIN (2 * DINNER * DIMX)             /* 8388608 */
#define N_WX ((DTRANK + 2 * DSTATE) * DINNER) /* 196608 */
#define N_WDT (DINNER * DTRANK)               /* 131072 */
__global__ __launch_bounds__(256) void cvt_weights(const float* __restrict__ w_in,
                                                   const float* __restrict__ w_x,
                                                   const float* __restrict__ w_dt,
                                                   u16* __restrict__ o_in,
                                                   u16* __restrict__ o_x,
                                                   u16* __restrict__ o_dt) {
    int i = (blockIdx.x * 256 + threadIdx.x) * 4;
    const float* s; u16* d;
    if (i < N_WIN) { s = w_in + i; d = o_in + i; }
    else if (i < N_WIN + N_WX) { s = w_x + (i - N_WIN); d = o_x + (i - N_WIN); }
    else if (i < N_WIN + N_WX + N_WDT) { s = w_dt + (i - N_WIN - N_WX); d = o_dt + (i - N_WIN - N_WX); }
    else return;
    float4 f = *(const float4*)s;
    u32 p0 = (u32)f2bf(f.x) | ((u32)f2bf(f.y) << 16);
    u32 p1 = (u32)f2bf(f.z) | ((u32)f2bf(f.w) << 16);
    *(uint2*)d = make_uint2(p0, p1);
}

__global__ __launch_bounds__(256) void cvt_bf16(const float* __restrict__ src,
                                                u16* __restrict__ dst, int n) {
    int i = (blockIdx.x * 256 + threadIdx.x) * 4;
    if (i < n) {
        float4 f = *(const float4*)(src + i);
        u32 p0 = (u32)f2bf(f.x) | ((u32)f2bf(f.y) << 16);
        u32 p1 = (u32)f2bf(f.z) | ((u32)f2bf(f.w) << 16);
        *(uint2*)(dst + i) = make_uint2(p0, p1);
    }
}

// ---------------- LayerNorm: 1 block per row of 1024, f32 in -> bf16 out ----------------
__global__ __launch_bounds__(256) void ln_kernel(const float* __restrict__ x,
                                                 const float* __restrict__ g,
                                                 const float* __restrict__ bta,
                                                 u16* __restrict__ xn) {
    int row = blockIdx.x;
    int tid = threadIdx.x;
    const float* xr = x + (size_t)row * DIMX;
    float4 v = *(const float4*)(xr + tid * 4);
    float s = v.x + v.y + v.z + v.w;
    float s2 = v.x * v.x + v.y * v.y + v.z * v.z + v.w * v.w;
#pragma unroll
    for (int off = 32; off >= 1; off >>= 1) {
        s  += __shfl_down(s, off);
        s2 += __shfl_down(s2, off);
    }
    __shared__ float ss[4], ss2[4];
    if ((tid & 63) == 0) { ss[tid >> 6] = s; ss2[tid >> 6] = s2; }
    __syncthreads();
    s  = ss[0] + ss[1] + ss[2] + ss[3];
    s2 = ss2[0] + ss2[1] + ss2[2] + ss2[3];
    float mu = s * (1.f / DIMX);
    float var = s2 * (1.f / DIMX) - mu * mu;
    float rs = rsqrtf(var + 1e-5f);
    float4 gv = *(const float4*)(g + tid * 4);
    float4 bv = *(const float4*)(bta + tid * 4);
    float o0 = (v.x - mu) * rs * gv.x + bv.x;
    float o1 = (v.y - mu) * rs * gv.y + bv.y;
    float o2 = (v.z - mu) * rs * gv.z + bv.z;
    float o3 = (v.w - mu) * rs * gv.w + bv.w;
    u32 p0 = (u32)f2bf(o0) | ((u32)f2bf(o1) << 16);
    u32 p1 = (u32)f2bf(o2) | ((u32)f2bf(o3) << 16);
    *(uint2*)(xn + (size_t)row * DIMX + tid * 4) = make_uint2(p0, p1);
}

// ------- bf16 MFMA GEMM, global_load_lds staging + XOR-swizzled LDS: C = A*B^T -------
template <int EPI>
__global__ __launch_bounds__(256) void gemm_bt(const u16* __restrict__ A,
                                               const u16* __restrict__ Bm,
                                               u16* __restrict__ C,
                                               float* __restrict__ Cf,
                                               u16* __restrict__ C2,
                                               const float* __restrict__ Xf,
                                               int M, int N, int K,
                                               int lda, int ldb, int ldc) {
    __shared__ __align__(16) u16 As[128 * 32];
    __shared__ __align__(16) u16 Bs[128 * 32];
    int tid = threadIdx.x;
    int bm = blockIdx.x, bn = blockIdx.y;
    int wave = tid >> 6, lane = tid & 63;
    int wm = (wave >> 1) * 64, wn = (wave & 1) * 64;
    int lr = lane & 15;
    int lq = lane >> 4;
    int srow = lane >> 2;
    int scol = (((lane & 3) ^ ((lane >> 3) & 3)) * 8);
    int rblk = (lq ^ ((lr >> 1) & 3)) * 8;

    f32x4 acc[4][4];
#pragma unroll
    for (int i = 0; i < 4; ++i)
#pragma unroll
        for (int j = 0; j < 4; ++j) acc[i][j] = (f32x4){0.f, 0.f, 0.f, 0.f};

    for (int k0 = 0; k0 < K; k0 += 32) {
#pragma unroll
        for (int rep = 0; rep < 2; ++rep) {
            int chunk = wave * 2 + rep;
            int arow = bm * 128 + chunk * 16 + srow;
            load_lds_16(A + (size_t)arow * lda + k0 + scol, &As[chunk * 512]);
            int brow = bn * 128 + chunk * 16 + srow;
            if (brow < N)
                load_lds_16(Bm + (size_t)brow * ldb + k0 + scol, &Bs[chunk * 512]);
        }
        __syncthreads();
        bf16x8 af[4], bfr[4];
#pragma unroll
        for (int i = 0; i < 4; ++i)
            af[i] = *(bf16x8*)(&As[(wm + i * 16 + lr) * 32 + rblk]);
#pragma unroll
        for (int j = 0; j < 4; ++j)
            bfr[j] = *(bf16x8*)(&Bs[(wn + j * 16 + lr) * 32 + rblk]);
#pragma unroll
        for (int i = 0; i < 4; ++i)
#pragma unroll
            for (int j = 0; j < 4; ++j)
                acc[i][j] = __builtin_amdgcn_mfma_f32_16x16x32_bf16(af[i], bfr[j], acc[i][j], 0, 0, 0);
        __syncthreads();
    }

#pragma unroll
    for (int i = 0; i < 4; ++i)
#pragma unroll
        for (int j = 0; j < 4; ++j) {
            int col = bn * 128 + wn + j * 16 + lr;
            if (col >= N) continue;
#pragma unroll
            for (int r = 0; r < 4; ++r) {
                int row = bm * 128 + wm + i * 16 + lq * 4 + r;
                float v = acc[i][j][r];
                size_t off = (size_t)row * ldc + col;
                if (EPI == 2) {
                    v += Xf[off];
                    Cf[off] = v;
                } else if (EPI == 3) {
                    if (col < DINNER) {
                        C[(size_t)row * DINNER + col] = f2bf(v);
                    } else {
                        float s = v / (1.f + __expf(-v));
                        C2[(size_t)row * DINNER + (col - DINNER)] = f2bf(s);
                    }
                } else {
                    C[off] = f2bf(v);
                }
            }
        }
}

// ------- Split-K variant for GEMM4 (N=96): f32 partials, ldc=96, grid.z = split -------
__global__ __launch_bounds__(256) void gemm_bt_splitk(const u16* __restrict__ A,
                                                      const u16* __restrict__ Bm,
                                                      float* __restrict__ Cp,
                                                      int M, int N, int K,
                                                      int lda, int ldb, int nsplit) {
    __shared__ __align__(16) u16 As[128 * 32];
    __shared__ __align__(16) u16 Bs[128 * 32];
    int tid = threadIdx.x;
    int bm = blockIdx.x, split = blockIdx.z;
    int ks = K / nsplit;
    int kbeg = split * ks, kend = kbeg + ks;
    int wave = tid >> 6, lane = tid & 63;
    int wm = (wave >> 1) * 64, wn = (wave & 1) * 64;
    int lr = lane & 15;
    int lq = lane >> 4;
    int srow = lane >> 2;
    int scol = (((lane & 3) ^ ((lane >> 3) & 3)) * 8);
    int rblk = (lq ^ ((lr >> 1) & 3)) * 8;

    f32x4 acc[4][4];
#pragma unroll
    for (int i = 0; i < 4; ++i)
#pragma unroll
        for (int j = 0; j < 4; ++j) acc[i][j] = (f32x4){0.f, 0.f, 0.f, 0.f};

    for (int k0 = kbeg; k0 < kend; k0 += 32) {
#pragma unroll
        for (int rep = 0; rep < 2; ++rep) {
            int chunk = wave * 2 + rep;
            int arow = bm * 128 + chunk * 16 + srow;
            load_lds_16(A + (size_t)arow * lda + k0 + scol, &As[chunk * 512]);
            int brow = chunk * 16 + srow;
            if (brow < N)
                load_lds_16(Bm + (size_t)brow * ldb + k0 + scol, &Bs[chunk * 512]);
        }
        __syncthreads();
        bf16x8 af[4], bfr[4];
#pragma unroll
        for (int i = 0; i < 4; ++i)
            af[i] = *(bf16x8*)(&As[(wm + i * 16 + lr) * 32 + rblk]);
#pragma unroll
        for (int j = 0; j < 4; ++j)
            bfr[j] = *(bf16x8*)(&Bs[(wn + j * 16 + lr) * 32 + rblk]);
#pragma unroll
        for (int i = 0; i < 4; ++i)
#pragma unroll
            for (int j = 0; j < 4; ++j)
                acc[i][j] = __builtin_amdgcn_mfma_f32_16x16x32_bf16(af[i], bfr[j], acc[i][j], 0, 0, 0);
        __syncthreads();
    }

#pragma unroll
    for (int i = 0; i < 4; ++i)
#pragma unroll
        for (int j = 0; j < 4; ++j) {
            int col = wn + j * 16 + lr;
            if (col >= N) continue;
#pragma unroll
            for (int r = 0; r < 4; ++r) {
                int row = bm * 128 + wm + i * 16 + lq * 4 + r;
                Cp[((size_t)split * M + row) * 96 + col] = acc[i][j][r];
            }
        }
}

// reduce 4 split-K partials -> bf16 xdbl
__global__ __launch_bounds__(256) void reduce4(const float* __restrict__ Cp,
                                               u16* __restrict__ xdbl) {
    int t = blockIdx.x * 256 + threadIdx.x;  // 8192*96
    const size_t S = (size_t)BL * 96;
    float s = Cp[t] + Cp[t + S] + Cp[t + 2 * S] + Cp[t + 3 * S];
    xdbl[t] = f2bf(s);
}

// ------- dedicated skinny-K GEMM: dt = softplus(xdbl[:, :64] * W_dt^T + b_dt) -------
__global__ __launch_bounds__(256) void dt_kernel(const u16* __restrict__ A,   // xdbl, lda=96
                                                 const u16* __restrict__ Bw,  // W_dt bf16 [2048][64]
                                                 const float* __restrict__ bias,
                                                 u16* __restrict__ C) {       // dt [8192][2048]
    __shared__ __align__(16) u16 Bs[128 * 64];  // 16 KB
    int tid = threadIdx.x;
    int bm = blockIdx.x, bn = blockIdx.y;
    int wave = tid >> 6, lane = tid & 63;
    int wm = (wave >> 1) * 64, wn = (wave & 1) * 64;
    int lr = lane & 15;
    int lq = lane >> 4;

    const u16* bsrc = Bw + (size_t)bn * 128 * 64;
    {
        int row = tid >> 1, bb = (tid & 1) * 4;
#pragma unroll
        for (int j = 0; j < 4; ++j) {
            int b = bb + j;
            *(uint4*)(&Bs[row * 64 + ((b ^ (row & 7)) * 8)]) =
                *(const uint4*)(bsrc + row * 64 + b * 8);
        }
    }

    bf16x8 af[4][2];
#pragma unroll
    for (int i = 0; i < 4; ++i)
#pragma unroll
        for (int kk = 0; kk < 2; ++kk)
            af[i][kk] = *(const bf16x8*)(A + (size_t)(bm * 128 + wm + i * 16 + lr) * 96 + kk * 32 + lq * 8);

    __syncthreads();

    f32x4 acc[4][4];
#pragma unroll
    for (int i = 0; i < 4; ++i)
#pragma unroll
        for (int j = 0; j < 4; ++j) acc[i][j] = (f32x4){0.f, 0.f, 0.f, 0.f};

#pragma unroll
    for (int kk = 0; kk < 2; ++kk) {
        bf16x8 bfr[4];
#pragma unroll
        for (int j = 0; j < 4; ++j)
            bfr[j] = *(bf16x8*)(&Bs[(wn + j * 16 + lr) * 64 + (((kk * 4 + lq) ^ (lr & 7)) * 8)]);
#pragma unroll
        for (int i = 0; i < 4; ++i)
#pragma unroll
            for (int j = 0; j < 4; ++j)
                acc[i][j] = __builtin_amdgcn_mfma_f32_16x16x32_bf16(af[i][kk], bfr[j], acc[i][j], 0, 0, 0);
    }

#pragma unroll
    for (int i = 0; i < 4; ++i)
#pragma unroll
        for (int j = 0; j < 4; ++j) {
            int col = bn * 128 + wn + j * 16 + lr;
            float bv = bias[col];
#pragma unroll
            for (int r = 0; r < 4; ++r) {
                int row = bm * 128 + wm + i * 16 + lq * 4 + r;
                float v = acc[i][j][r] + bv;
                v = (v > 15.f) ? v : __logf(1.f + __expf(v));
                C[(size_t)row * DINNER + col] = f2bf(v);
            }
        }
}

// ---------------- Depthwise causal conv (k=4) + bias + SiLU, 8 channels/thread ----------------
__global__ __launch_bounds__(256) void conv_silu(const u16* __restrict__ u,
                                                 const float* __restrict__ cw,
                                                 const float* __restrict__ cb,
                                                 u16* __restrict__ uc) {
    size_t t = (size_t)blockIdx.x * 256 + threadIdx.x;  // over BL * DINNER/8
    int c8 = (int)(t & (DINNER / 8 - 1)) * 8;
    size_t bl = t >> 8;
    int l = (int)(bl & (LSEQ - 1));
    int b = (int)(bl >> 11);

    float wk[8][4];
#pragma unroll
    for (int i = 0; i < 8; ++i) {
        float4 w = *(const float4*)(cw + (c8 + i) * DCONV);
        wk[i][0] = w.x; wk[i][1] = w.y; wk[i][2] = w.z; wk[i][3] = w.w;
    }
    float acc[8];
    {
        float4 b0 = *(const float4*)(cb + c8);
        float4 b1 = *(const float4*)(cb + c8 + 4);
        acc[0] = b0.x; acc[1] = b0.y; acc[2] = b0.z; acc[3] = b0.w;
        acc[4] = b1.x; acc[5] = b1.y; acc[6] = b1.z; acc[7] = b1.w;
    }
#pragma unroll
    for (int k = 0; k < DCONV; ++k) {
        int ls = l + k - (DCONV - 1);
        if (ls >= 0) {
            float uf[8];
            unpack8(*(const bf16x8*)(u + ((size_t)b * LSEQ + ls) * DINNER + c8), uf);
#pragma unroll
            for (int i = 0; i < 8; ++i) acc[i] += uf[i] * wk[i][k];
        }
    }
    float o[8];
#pragma unroll
    for (int i = 0; i < 8; ++i) o[i] = acc[i] / (1.f + __expf(-acc[i]));
    *(uint4*)(uc + bl * DINNER + c8) = pack8(o);
}

// ---------------- Chunked selective scan, thread-per-d; P/S/Hin in bf16 ----------------
// (round-9 structure: scalar streaming loads, dynamic-index bc loop — no spills)
__global__ __launch_bounds__(256, 4) void scan_pass1(const u16* __restrict__ dt,
                                                     const u16* __restrict__ uc,
                                                     const u16* __restrict__ xdbl,
                                                     const float* __restrict__ Alog,
                                                     u16* __restrict__ Pa,
                                                     u16* __restrict__ Sa) {
    __shared__ __align__(16) u16 bc[CLEN * 16];  // B tile [l][n]
    int tid = threadIdx.x;
    int d = blockIdx.x * 256 + tid;
    int c = blockIdx.y, b = blockIdx.z;
    size_t base = (size_t)b * LSEQ + (size_t)c * CLEN;
    if (tid < CLEN * 2)
        ((uint4*)bc)[tid] = *(const uint4*)(xdbl + (base + (tid >> 1)) * 96 + 64 + (tid & 1) * 8);
    __syncthreads();

    float a[16];
    const float* Ap = Alog + (size_t)d * DSTATE;
#pragma unroll
    for (int n = 0; n < 16; ++n) a[n] = -__expf(Ap[n]);
    float h[16], P[16];
#pragma unroll
    for (int n = 0; n < 16; ++n) { h[n] = 0.f; P[n] = 1.f; }

    const u16* dtp = dt + base * DINNER + d;
    const u16* ucp = uc + base * DINNER + d;
    for (int l = 0; l < CLEN; ++l) {
        float dtv = bf2f(dtp[(size_t)l * DINNER]);
        float du  = dtv * bf2f(ucp[(size_t)l * DINNER]);
        float Bv[16];
        unpack8(*(bf16x8*)(&bc[l * 16]), Bv);
        unpack8(*(bf16x8*)(&bc[l * 16 + 8]), Bv + 8);
#pragma unroll
        for (int n = 0; n < 16; ++n) {
            float dA = __expf(dtv * a[n]);
            h[n] = dA * h[n] + du * Bv[n];
            P[n] *= dA;
        }
    }
    size_t idx = (((size_t)b * CCHUNK + c) * DINNER + d) * DSTATE;
    *(uint4*)(Pa + idx)     = pack8(P);
    *(uint4*)(Pa + idx + 8) = pack8(P + 8);
    *(uint4*)(Sa + idx)     = pack8(h);
    *(uint4*)(Sa + idx + 8) = pack8(h + 8);
}

__global__ __launch_bounds__(256) void scan_combine(u16* __restrict__ Pa,
                                                    const u16* __restrict__ Sa) {
    int t = blockIdx.x * 256 + threadIdx.x;  // over B * DINNER * 16 = 131072
    int b = t >> 15, dn = t & 32767;
    size_t base = (size_t)b * CCHUNK * (DINNER * DSTATE) + dn;
    float h = 0.f;
#pragma unroll
    for (int c = 0; c < CCHUNK; ++c) {
        size_t i = base + (size_t)c * (DINNER * DSTATE);
        float p = bf2f(Pa[i]), s = bf2f(Sa[i]);
        Pa[i] = f2bf(h);  // h_in for this chunk
        h = p * h + s;
    }
}

__global__ __launch_bounds__(256, 4) void scan_pass3(const u16* __restrict__ dt,
                                                     const u16* __restrict__ uc,
                                                     const u16* __restrict__ sz,
                                                     const u16* __restrict__ xdbl,
                                                     const float* __restrict__ Alog,
                                                     const float* __restrict__ Dv,
                                                     const u16* __restrict__ Hin,
                                                     u16* __restrict__ y) {
    __shared__ __align__(16) u16 bc[CLEN * 32];  // [l][0:16]=B, [16:32]=C
    int tid = threadIdx.x;
    int d = blockIdx.x * 256 + tid;
    int c = blockIdx.y, b = blockIdx.z;
    size_t base = (size_t)b * LSEQ + (size_t)c * CLEN;
    ((uint4*)bc)[tid] = *(const uint4*)(xdbl + (base + (tid >> 2)) * 96 + 64 + (tid & 3) * 8);
    __syncthreads();

    float a[16];
    const float* Ap = Alog + (size_t)d * DSTATE;
#pragma unroll
    for (int n = 0; n < 16; ++n) a[n] = -__expf(Ap[n]);
    float Dd = Dv[d];
    float h[16];
    size_t idx = (((size_t)b * CCHUNK + c) * DINNER + d) * DSTATE;
    unpack8(*(bf16x8*)(Hin + idx), h);
    unpack8(*(bf16x8*)(Hin + idx + 8), h + 8);

    const u16* dtp = dt + base * DINNER + d;
    const u16* ucp = uc + base * DINNER + d;
    const u16* szp = sz + base * DINNER + d;
    u16* yp        = y  + base * DINNER + d;
    for (int l = 0; l < CLEN; ++l) {
        float dtv = bf2f(dtp[(size_t)l * DINNER]);
        float ucv = bf2f(ucp[(size_t)l * DINNER]);
        float du  = dtv * ucv;
        float Bv[16], Cv[16];
        unpack8(*(bf16x8*)(&bc[l * 32]), Bv);
        unpack8(*(bf16x8*)(&bc[l * 32 + 8]), Bv + 8);
        unpack8(*(bf16x8*)(&bc[l * 32 + 16]), Cv);
        unpack8(*(bf16x8*)(&bc[l * 32 + 24]), Cv + 8);
        float yv = 0.f;
#pragma unroll
        for (int n = 0; n < 16; ++n) {
            float dA = __expf(dtv * a[n]);
            h[n] = dA * h[n] + du * Bv[n];
            yv += h[n] * Cv[n];
        }
        float szv = bf2f(szp[(size_t)l * DINNER]);  // already silu(z)
        yp[(size_t)l * DINNER] = f2bf((yv + ucv * Dd) * szv);
    }
}

extern "C" void kernel_launch(void* const* d_in, const int* in_sizes, int n_in,
                              void* d_out, int out_size, void* d_ws, size_t ws_size,
                              hipStream_t stream) {
    const float* x      = (const float*)d_in[0];
    const float* ln_g   = (const float*)d_in[1];
    const float* ln_b   = (const float*)d_in[2];
    const float* W_in   = (const float*)d_in[3];
    const float* conv_w = (const float*)d_in[4];
    const float* conv_b = (const float*)d_in[5];
    const float* W_x    = (const float*)d_in[6];
    const float* W_dt   = (const float*)d_in[7];
    const float* b_dt   = (const float*)d_in[8];
    const float* A_log  = (const float*)d_in[9];
    const float* Dvec   = (const float*)d_in[10];
    const float* W_out  = (const float*)d_in[11];
    float* out = (float*)d_out;

    // ws (130 MB):
    //   [0, 1.5MB)       xdbl (bf16)
    //   [1.5MB, 1.75MB)  W_dt bf16
    //   [2,34)           u (dead after conv; y reuses)
    //   [34,66)          sz = silu(z)  (dead after pass3; W_out bf16 here)
    //   [66,98)          uc
    //   [98,130)         dt  -- pre-dt carries W_in bf16 [98,106), W_x bf16 [106,106.4)
    // d_out (32MB f32): xn bf16 [0:16MB] (LN->GEMM1); splitK partials f32 [0:12.6MB];
    // Pa bf16 [0:8.4MB](->Hin in-place), Sa bf16 [16:24.4MB]; final GEMM overwrites.
    char* ws = (char*)d_ws;
    u16* xdbl   = (u16*)(ws);
    u16* wdt_b  = (u16*)(ws + (size_t)1572864);
    u16* u      = (u16*)(ws + (size_t)(2u << 20));
    u16* y      = u;
    u16* sz     = (u16*)(ws + (size_t)(34u << 20));
    u16* wout_b = (u16*)(ws + (size_t)(34u << 20));
    u16* uc     = (u16*)(ws + (size_t)(66u << 20));
    u16* dt     = (u16*)(ws + (size_t)(98u << 20));
    u16* win_b  = (u16*)(ws + (size_t)(98u << 20));
    u16* wx_b   = (u16*)(ws + (size_t)(106u << 20));
    u16* xn     = (u16*)d_out;
    float* c4p  = (float*)d_out;
    u16* Pa     = (u16*)d_out;
    u16* Sa     = (u16*)((char*)d_out + (size_t)(16u << 20));

    // 0. weight conversions (f32 -> bf16), one batched launch
    cvt_weights<<<(N_WIN + N_WX + N_WDT) / 1024, 256, 0, stream>>>(W_in, W_x, W_dt,
                                                                   win_b, wx_b, wdt_b);

    // 1. LayerNorm (f32 -> bf16)
    ln_kernel<<<BL, 256, 0, stream>>>(x, ln_g, ln_b, xn);

    // 2. [u | silu(z)] = xn * W_in^T   (M=8192, N=4096, K=1024)
    gemm_bt<3><<<dim3(64, 32), 256, 0, stream>>>(xn, win_b, u, nullptr, sz, nullptr,
                                                 BL, 2 * DINNER, DIMX, DIMX, DIMX, 2 * DINNER);

    // 3. depthwise conv + bias + silu (8 ch/thread)
    conv_silu<<<(BL * DINNER / 8) / 256, 256, 0, stream>>>(u, conv_w, conv_b, uc);

    // 4. x_dbl = uc * W_x^T  (M=8192, N=96, K=2048), split-K x4 + reduce
    gemm_bt_splitk<<<dim3(64, 1, 4), 256, 0, stream>>>(uc, wx_b, c4p,
                                                       BL, DTRANK + 2 * DSTATE, DINNER,
                                                       DINNER, DINNER, 4);
    reduce4<<<(BL * 96) / 256, 256, 0, stream>>>(c4p, xdbl);

    // 5. dt = softplus(x_dbl[:, :64] * W_dt^T + b_dt)
    dt_kernel<<<dim3(64, 16), 256, 0, stream>>>(xdbl, wdt_b, b_dt, dt);

    // 6. chunked selective scan -> y (round-9 structure)
    scan_pass1<<<dim3(DINNER / 256, CCHUNK, BB), 256, 0, stream>>>(dt, uc, xdbl, A_log, Pa, Sa);
    scan_combine<<<(BB * DINNER * DSTATE) / 256, 256, 0, stream>>>(Pa, Sa);
    scan_pass3<<<dim3(DINNER / 256, CCHUNK, BB), 256, 0, stream>>>(dt, uc, sz, xdbl, A_log, Dvec, Pa, y);

    // 6b. convert W_out now that sz is dead
    cvt_bf16<<<2048, 256, 0, stream>>>(W_out, wout_b, DIMX * DINNER);

    // 7. out = x + y * W_out^T  (M=8192, N=1024, K=2048), f32 output
    gemm_bt<2><<<dim3(64, 8), 256, 0, stream>>>(y, wout_b, nullptr, out, nullptr, x,
                                                BL, DIMX, DINNER, DINNER, DINNER, DIMX);
}